// Round 7
// baseline (58.096 us; speedup 1.0000x reference)
//
#include <hip/hip_runtime.h>
#include <math.h>
#include <stdint.h>

#define NUM_BINS 1000
#define MAX_MZ_F 1000.0f
#define B_ROWS 8192
#define N_COLS 2048
#define BLOCK 256
#define NBLOCKS 2048
#define NPAIRS (NBLOCKS * 2)             // 4096 wave-pairs
#define ROWS_PER_PAIR (B_ROWS / NPAIRS)  // 2

// Fixed-point scale for intensity accumulation (integer LDS atomics).
// Bin sums < 2048, so 2^20 scale stays < 2^31. Quantization error ~5e-7/elem.
#define QSCALE_F 1048576.0f
#define QINV_F   (1.0f / 1048576.0f)

// log1p(exp(-1)) and ln(2) as f32-accurate constants
#define BCE_PE1 0.31326168751822286f
#define BCE_PE0 0.69314718055994531f

// Bit-identical to reference: (int)(mz / 1000.0f * 999.0f)
__device__ __forceinline__ int bin_of(float mz) {
    return (int)(mz / MAX_MZ_F * 999.0f);
}

__device__ __forceinline__ float wave_reduce_add(float v) {
    #pragma unroll
    for (int off = 32; off > 0; off >>= 1)
        v += __shfl_xor(v, off, 64);
    return v;
}

// 2 waves share one histogram pair -> 16 KB/block -> 8 blocks/CU -> 32 waves/CU.
__global__ __launch_bounds__(BLOCK, 8) void hybrid_loss_main(
    const float* __restrict__ pred_mz,
    const float* __restrict__ pred_in,
    const float* __restrict__ true_mz,
    const float* __restrict__ true_in,
    float4* __restrict__ part)   // part[row] = {cosl, bce, hub, cnt}
{
    // hist[p][0..1023] = pred bins, hist[p][1024..2047] = true bins (pair p)
    __shared__ unsigned int hist[2][2048];
    __shared__ float scr[2][2][6];   // [pair][waveInPair][6 partials]

    const int tid   = threadIdx.x;
    const int wv    = tid >> 6;
    const int lane  = tid & 63;
    const int pib   = wv >> 1;            // pair in block: 0/1
    const int wip   = wv & 1;             // wave in pair:  0/1
    const int plane = (wip << 6) | lane;  // 0..127 within pair
    const int pair  = blockIdx.x * 2 + pib;

    unsigned int* h = hist[pib];

    for (int r = 0; r < ROWS_PER_PAIR; ++r) {
        const int row = r * NPAIRS + pair;   // concurrent pairs sweep contiguous rows

        // ---- zero: 2048 u32 = 512 uint4; 4 per lane over 128 lanes ----
        {
            uint4 z = make_uint4(0u, 0u, 0u, 0u);
            uint4* h4 = (uint4*)h;
            #pragma unroll
            for (int j = 0; j < 4; ++j) h4[plane + 128 * j] = z;
        }
        __syncthreads();

        // ---- binning: 4 float4 per lane per array (512 float4 / 128 lanes) ----
        {
            const float4* pmz = (const float4*)(pred_mz + (size_t)row * N_COLS);
            const float4* pin = (const float4*)(pred_in + (size_t)row * N_COLS);
            const float4* tmz = (const float4*)(true_mz + (size_t)row * N_COLS);
            const float4* tin = (const float4*)(true_in + (size_t)row * N_COLS);
            #pragma unroll
            for (int k = 0; k < 4; ++k) {
                const int idx = plane + 128 * k;
                float4 m = pmz[idx];
                float4 v = pin[idx];
                float4 s = tmz[idx];
                float4 u = tin[idx];
                atomicAdd(&h[bin_of(m.x)], __float2uint_rn(v.x * QSCALE_F));
                atomicAdd(&h[bin_of(m.y)], __float2uint_rn(v.y * QSCALE_F));
                atomicAdd(&h[bin_of(m.z)], __float2uint_rn(v.z * QSCALE_F));
                atomicAdd(&h[bin_of(m.w)], __float2uint_rn(v.w * QSCALE_F));
                atomicAdd(&h[1024 + bin_of(s.x)], __float2uint_rn(u.x * QSCALE_F));
                atomicAdd(&h[1024 + bin_of(s.y)], __float2uint_rn(u.y * QSCALE_F));
                atomicAdd(&h[1024 + bin_of(s.z)], __float2uint_rn(u.z * QSCALE_F));
                atomicAdd(&h[1024 + bin_of(s.w)], __float2uint_rn(u.w * QSCALE_F));
            }
        }
        __syncthreads();

        // ---- per-bin loss terms: 8 bins per lane (1024 / 128) ----
        float dot = 0.f, pn2 = 0.f, tn2 = 0.f, bce = 0.f, hub = 0.f, cnt = 0.f;
        #pragma unroll
        for (int k = 0; k < 8; ++k) {
            const int i = plane + 128 * k;
            unsigned int pq = h[i];
            unsigned int tq = h[1024 + i];
            float p = (float)pq * QINV_F;
            float t = (float)tq * QINV_F;
            float valid = (i < NUM_BINS) ? 1.0f : 0.0f;  // bins 1000..1023 stay zero
            dot += p * t;
            pn2 += p * p;
            tn2 += t * t;
            float te = (tq != 0u) ? 1.0f : 0.0f;
            float bt = (pq != 0u) ? (1.0f - te + BCE_PE1) : BCE_PE0;
            bce += valid * bt;
            float d  = p - t;
            float ad = fabsf(d);
            float hh = (ad < 1.0f) ? (0.5f * d * d) : (ad - 0.5f);
            hub += hh * te;
            cnt += te;
        }

        // ---- wave reduce, pair-combine via tiny LDS scratch ----
        dot = wave_reduce_add(dot);
        pn2 = wave_reduce_add(pn2);
        tn2 = wave_reduce_add(tn2);
        bce = wave_reduce_add(bce);
        hub = wave_reduce_add(hub);
        cnt = wave_reduce_add(cnt);

        if (lane == 0) {
            scr[pib][wip][0] = dot; scr[pib][wip][1] = pn2; scr[pib][wip][2] = tn2;
            scr[pib][wip][3] = bce; scr[pib][wip][4] = hub; scr[pib][wip][5] = cnt;
        }
        __syncthreads();

        if (wip == 0 && lane == 0) {
            float a0 = scr[pib][0][0] + scr[pib][1][0];
            float a1 = scr[pib][0][1] + scr[pib][1][1];
            float a2 = scr[pib][0][2] + scr[pib][1][2];
            float a3 = scr[pib][0][3] + scr[pib][1][3];
            float a4 = scr[pib][0][4] + scr[pib][1][4];
            float a5 = scr[pib][0][5] + scr[pib][1][5];
            float pn = fmaxf(sqrtf(a1), 1e-8f);
            float tn = fmaxf(sqrtf(a2), 1e-8f);
            float4 rr;
            rr.x = 1.0f - a0 / (pn * tn);
            rr.y = a3; rr.z = a4; rr.w = a5;
            part[row] = rr;
        }
        // scr reuse is protected by the next iteration's zero-phase barrier
        // (a wave must pass it before overwriting scr, and the combiner
        // reaches it only after reading scr).
    }
}

__global__ __launch_bounds__(256) void hybrid_loss_reduce(
    const float4* __restrict__ part,
    float* __restrict__ out)
{
    __shared__ double xr[4][4];
    const int tid = threadIdx.x;

    double c = 0.0, b = 0.0, h = 0.0, n = 0.0;
    for (int i = tid; i < B_ROWS; i += 256) {
        float4 v = part[i];
        c += (double)v.x; b += (double)v.y; h += (double)v.z; n += (double)v.w;
    }
    #pragma unroll
    for (int off = 32; off > 0; off >>= 1) {
        c += __shfl_xor(c, off, 64);
        b += __shfl_xor(b, off, 64);
        h += __shfl_xor(h, off, 64);
        n += __shfl_xor(n, off, 64);
    }
    const int wave = tid >> 6;
    const int lane = tid & 63;
    if (lane == 0) { xr[wave][0] = c; xr[wave][1] = b; xr[wave][2] = h; xr[wave][3] = n; }
    __syncthreads();

    if (tid == 0) {
        double C = 0.0, Bs = 0.0, H = 0.0, Nn = 0.0;
        #pragma unroll
        for (int w = 0; w < 4; ++w) {
            C += xr[w][0]; Bs += xr[w][1]; H += xr[w][2]; Nn += xr[w][3];
        }
        double loss_cos  = C / (double)B_ROWS;
        double loss_peak = Bs / ((double)B_ROWS * (double)NUM_BINS);
        double cnt       = Nn < 1.0 ? 1.0 : Nn;
        double loss_int  = H / cnt;
        out[0] = (float)(0.4 * loss_cos + 0.3 * loss_peak + 0.2 * loss_int);
    }
}

extern "C" void kernel_launch(void* const* d_in, const int* in_sizes, int n_in,
                              void* d_out, int out_size, void* d_ws, size_t ws_size,
                              hipStream_t stream) {
    const float* pred_mz = (const float*)d_in[0];
    const float* pred_in = (const float*)d_in[1];
    const float* true_mz = (const float*)d_in[2];
    const float* true_in = (const float*)d_in[3];
    float4* part = (float4*)d_ws;   // 8192 * 16 B = 128 KiB
    float* out = (float*)d_out;

    hybrid_loss_main<<<NBLOCKS, BLOCK, 0, stream>>>(pred_mz, pred_in, true_mz, true_in, part);
    hybrid_loss_reduce<<<1, 256, 0, stream>>>(part, out);
}

// Round 8
// 54.989 us; speedup vs baseline: 1.0565x; 1.0565x over previous
//
#include <hip/hip_runtime.h>
#include <math.h>
#include <stdint.h>

#define NUM_BINS 1000
#define MAX_MZ_F 1000.0f
#define B_ROWS 8192
#define N_COLS 2048
#define BLOCK 256
#define NBLOCKS 1024
#define NWAVES (NBLOCKS * 4)      // 4096 waves
#define ROWS_PER_WAVE (B_ROWS / NWAVES)  // 2

// Fixed-point scale for intensity accumulation (integer LDS atomics).
// Bin sums < 2048, so 2^20 scale stays < 2^31. Quantization error ~5e-7/elem.
#define QSCALE_F 1048576.0f
#define QINV_F   (1.0f / 1048576.0f)

// log1p(exp(-1)) and ln(2) as f32-accurate constants
#define BCE_PE1 0.31326168751822286f
#define BCE_PE0 0.69314718055994531f

// Bit-identical to reference: (int)(mz / 1000.0f * 999.0f)
__device__ __forceinline__ int bin_of(float mz) {
    return (int)(mz / MAX_MZ_F * 999.0f);
}

__device__ __forceinline__ float wave_reduce_add(float v) {
    #pragma unroll
    for (int off = 32; off > 0; off >>= 1)
        v += __shfl_xor(v, off, 64);
    return v;
}

// Wave-private histograms, barrier-free: the R6 structure that saturates the
// DS-atomic pipe (measured 1.01 cyc per atomic lane-op = the per-CU serial
// atomic-unit floor; occupancy proven irrelevant in R7).
__global__ __launch_bounds__(BLOCK, 4) void hybrid_loss_main(
    const float* __restrict__ pred_mz,
    const float* __restrict__ pred_in,
    const float* __restrict__ true_mz,
    const float* __restrict__ true_in,
    float4* __restrict__ part)   // part[row] = {cosl, bce, hub, cnt}
{
    // Per-WAVE private integer histograms: [0..1023]=pred, [1024..2047]=true.
    // Wave-private + wave-lockstep DS ordering => no __syncthreads needed.
    __shared__ unsigned int hist[4][2048];

    const int tid  = threadIdx.x;
    const int wv   = tid >> 6;
    const int lane = tid & 63;
    const int w    = blockIdx.x * 4 + wv;

    unsigned int* h = hist[wv];

    for (int r = 0; r < ROWS_PER_WAVE; ++r) {
        const int row = r * NWAVES + w;   // concurrent waves sweep contiguous rows

        // ---- zero both hists: 512 uint4, 8 per lane, stride-64 (conflict-free) ----
        {
            uint4 z = make_uint4(0u, 0u, 0u, 0u);
            uint4* h4 = (uint4*)h;
            #pragma unroll
            for (int j = 0; j < 8; ++j) h4[lane + 64 * j] = z;
        }

        // ---- binning: quantize to fixed-point, integer LDS atomics ----
        {
            const float4* pmz = (const float4*)(pred_mz + (size_t)row * N_COLS);
            const float4* pin = (const float4*)(pred_in + (size_t)row * N_COLS);
            const float4* tmz = (const float4*)(true_mz + (size_t)row * N_COLS);
            const float4* tin = (const float4*)(true_in + (size_t)row * N_COLS);
            #pragma unroll 4
            for (int k = 0; k < 8; ++k) {
                const int idx = lane + 64 * k;
                float4 m = pmz[idx];
                float4 v = pin[idx];
                float4 s = tmz[idx];
                float4 u = tin[idx];
                atomicAdd(&h[bin_of(m.x)], __float2uint_rn(v.x * QSCALE_F));
                atomicAdd(&h[bin_of(m.y)], __float2uint_rn(v.y * QSCALE_F));
                atomicAdd(&h[bin_of(m.z)], __float2uint_rn(v.z * QSCALE_F));
                atomicAdd(&h[bin_of(m.w)], __float2uint_rn(v.w * QSCALE_F));
                atomicAdd(&h[1024 + bin_of(s.x)], __float2uint_rn(u.x * QSCALE_F));
                atomicAdd(&h[1024 + bin_of(s.y)], __float2uint_rn(u.y * QSCALE_F));
                atomicAdd(&h[1024 + bin_of(s.z)], __float2uint_rn(u.z * QSCALE_F));
                atomicAdd(&h[1024 + bin_of(s.w)], __float2uint_rn(u.w * QSCALE_F));
            }
        }

        // ---- per-bin loss terms: lane handles bins {lane, lane+64, ...} ----
        // Same-wave DS ops are in-order; hist is wave-private => reads see all adds.
        float dot = 0.f, pn2 = 0.f, tn2 = 0.f, bce = 0.f, hub = 0.f, cnt = 0.f;
        #pragma unroll
        for (int k = 0; k < 16; ++k) {
            const int i = lane + 64 * k;
            unsigned int pq = h[i];
            unsigned int tq = h[1024 + i];
            float p = (float)pq * QINV_F;
            float t = (float)tq * QINV_F;
            float valid = (i < NUM_BINS) ? 1.0f : 0.0f;  // only k==15 partial
            dot += p * t;
            pn2 += p * p;
            tn2 += t * t;
            float te = (tq != 0u) ? 1.0f : 0.0f;
            float bt = (pq != 0u) ? (1.0f - te + BCE_PE1) : BCE_PE0;
            bce += valid * bt;
            float d  = p - t;
            float ad = fabsf(d);
            float hh = (ad < 1.0f) ? (0.5f * d * d) : (ad - 0.5f);
            hub += hh * te;
            cnt += te;
        }

        // ---- wave reduction, lane 0 writes the row partial ----
        dot = wave_reduce_add(dot);
        pn2 = wave_reduce_add(pn2);
        tn2 = wave_reduce_add(tn2);
        bce = wave_reduce_add(bce);
        hub = wave_reduce_add(hub);
        cnt = wave_reduce_add(cnt);

        if (lane == 0) {
            float pn = fmaxf(sqrtf(pn2), 1e-8f);
            float tn = fmaxf(sqrtf(tn2), 1e-8f);
            float4 rr;
            rr.x = 1.0f - dot / (pn * tn);
            rr.y = bce; rr.z = hub; rr.w = cnt;
            part[row] = rr;
        }
    }
}

__global__ __launch_bounds__(256) void hybrid_loss_reduce(
    const float4* __restrict__ part,
    float* __restrict__ out)
{
    __shared__ double xr[4][4];
    const int tid = threadIdx.x;

    double c = 0.0, b = 0.0, h = 0.0, n = 0.0;
    for (int i = tid; i < B_ROWS; i += 256) {
        float4 v = part[i];
        c += (double)v.x; b += (double)v.y; h += (double)v.z; n += (double)v.w;
    }
    #pragma unroll
    for (int off = 32; off > 0; off >>= 1) {
        c += __shfl_xor(c, off, 64);
        b += __shfl_xor(b, off, 64);
        h += __shfl_xor(h, off, 64);
        n += __shfl_xor(n, off, 64);
    }
    const int wave = tid >> 6;
    const int lane = tid & 63;
    if (lane == 0) { xr[wave][0] = c; xr[wave][1] = b; xr[wave][2] = h; xr[wave][3] = n; }
    __syncthreads();

    if (tid == 0) {
        double C = 0.0, Bs = 0.0, H = 0.0, Nn = 0.0;
        #pragma unroll
        for (int w = 0; w < 4; ++w) {
            C += xr[w][0]; Bs += xr[w][1]; H += xr[w][2]; Nn += xr[w][3];
        }
        double loss_cos  = C / (double)B_ROWS;
        double loss_peak = Bs / ((double)B_ROWS * (double)NUM_BINS);
        double cnt       = Nn < 1.0 ? 1.0 : Nn;
        double loss_int  = H / cnt;
        out[0] = (float)(0.4 * loss_cos + 0.3 * loss_peak + 0.2 * loss_int);
    }
}

extern "C" void kernel_launch(void* const* d_in, const int* in_sizes, int n_in,
                              void* d_out, int out_size, void* d_ws, size_t ws_size,
                              hipStream_t stream) {
    const float* pred_mz = (const float*)d_in[0];
    const float* pred_in = (const float*)d_in[1];
    const float* true_mz = (const float*)d_in[2];
    const float* true_in = (const float*)d_in[3];
    float4* part = (float4*)d_ws;   // 8192 * 16 B = 128 KiB
    float* out = (float*)d_out;

    hybrid_loss_main<<<NBLOCKS, BLOCK, 0, stream>>>(pred_mz, pred_in, true_mz, true_in, part);
    hybrid_loss_reduce<<<1, 256, 0, stream>>>(part, out);
}